// Round 19
// baseline (173.394 us; speedup 1.0000x reference)
//
#include <hip/hip_runtime.h>
#include <hip/hip_bf16.h>

// Problem constants
#define BGR   256                 // graphs
#define NPG1  512                 // nodes per graph (input)
#define DEG   16
#define EPG   (NPG1 * DEG)        // 8192 edges per graph
#define LB    5                   // lookback features
#define DIM   64
#define OUTF  6
#define NN    (BGR * NPG1)        // 131,072
#define EDG   (BGR * EPG)         // 2,097,152
#define K1    410                 // ceil(0.8*512)
#define K2    328                 // ceil(0.8*410)
#define N1    (BGR * K1)          // 104,960 (compact node space)
#define K1P   (K1 + 1)            // padded stride: row K1 of each graph = zeros
#define NR    (BGR * K1P)         // 105,216 padded rows (= 1644 * 64)
#define CSRW  48                  // layer-2 CSR slots per pooled node
#define CSRW1 52                  // layer-1 CSR slots (P[in-deg>52] ~ 3e-8)
#define GRIDW (NR / 64)           // 1644 gemm blocks (64 rows each)
#define GRIDA (N1 / 16)           // 6560 gather2 blocks

// ---------------------------------------------------------------------------
// s1_mega (one block per graph, 2 blocks/CU): the ENTIRE layer-1 front-end.
//   stage x -> CSR1 build -> conv1 score (lane=node, mean in LDS) -> rank ->
//   CSR2 derived from CSR1 (owner thread writes its 96B global row directly,
//   entries + sentinel fill, plus indeg) -> kept-row recompute + h1p +
//   readout x1.  LDS 79.9 KB; red arrays overlay lcsr1 (dead by then).
__global__ __launch_bounds__(512, 4)
void s1_mega_kernel(const float* __restrict__ x,
                    const int* __restrict__ eidx,
                    const float* __restrict__ Wl,
                    const float* __restrict__ bl,
                    const float* __restrict__ Wr,
                    const float* __restrict__ pw,
                    float* __restrict__ h1p,
                    float* __restrict__ x1buf,
                    unsigned short* __restrict__ csr2,
                    int* __restrict__ indeg) {
    __shared__ __align__(16) float xl[NPG1 * LB];              // 10 KB
    __shared__ __align__(16) float ml[NPG1 * LB];              // 10 KB
    __shared__ __align__(16) unsigned short lcsr1[CSRW1 * NPG1]; // 53.25 KB
    __shared__ int   lcnt[NPG1];                               // 2 KB
    __shared__ __align__(16) float sc[NPG1];                   // 2 KB
    __shared__ int   rnk[NPG1];                                // 2 KB
    // red arrays overlay lcsr1 (guarded by a barrier after last lcsr1 read)
    float* redmx = (float*)lcsr1;                              // 2 KB
    float* redsm = redmx + 8 * DIM;                            // 2 KB

    const int g = blockIdx.x, t = threadIdx.x;
    const int wid = t >> 6, lane = t & 63;
    const int* __restrict__ src = eidx;
    const int* __restrict__ dst = eidx + EDG;

    {   // stage x, init counters, zero h1p pad row
        const float4* x4 = (const float4*)(x + (size_t)g * (NPG1 * LB));
        float4* xl4 = (float4*)xl;
        #pragma unroll
        for (int k = 0; k < 2; ++k) {
            int i = k * 512 + t;
            if (i < NPG1 * LB / 4) xl4[i] = x4[i];
        }
        lcnt[t] = 0;
        if (t < DIM) h1p[((size_t)g * K1P + K1) * DIM + t] = 0.f;
    }
    __syncthreads();

    // Edge pass (the only one): build CSR1 [slot][node] in LDS.
    const int ebase = g * EPG;
    for (int k = 0; k < EPG / 512; ++k) {
        int e = ebase + k * 512 + t;
        int s = src[e] & (NPG1 - 1);
        int d = dst[e] & (NPG1 - 1);
        int slot = atomicAdd(&lcnt[d], 1);
        if (slot < CSRW1) lcsr1[slot * NPG1 + d] = (unsigned short)s;
    }
    __syncthreads();

    // Score (lane = node): gather neighbors from CSR1, mean -> ml, conv1+score.
    {
        const int dgf = lcnt[t];
        const int dg  = min(dgf, CSRW1);
        float s0 = 0.f, s1 = 0.f, s2 = 0.f, s3 = 0.f, s4 = 0.f;
        for (int k = 0; k < dg; ++k) {
            int s = lcsr1[k * NPG1 + t];
            const float* xp = xl + s * LB;
            s0 += xp[0]; s1 += xp[1]; s2 += xp[2]; s3 += xp[3]; s4 += xp[4];
        }
        const float invd = 1.f / fmaxf((float)dgf, 1.f);
        float m[LB]  = { s0 * invd, s1 * invd, s2 * invd, s3 * invd, s4 * invd };
        float xv[LB];
        #pragma unroll
        for (int j = 0; j < LB; ++j) { xv[j] = xl[t * LB + j]; ml[t * LB + j] = m[j]; }

        const float4* Wl4 = (const float4*)Wl;
        const float4* Wr4 = (const float4*)Wr;
        const float4* bl4 = (const float4*)bl;
        const float4* pw4 = (const float4*)pw;
        float p = 0.f, q = 0.f;
        #pragma unroll 4
        for (int d4 = 0; d4 < DIM / 4; ++d4) {
            float4 bb = bl4[d4];
            float4 ww = pw4[d4];
            float4 h = bb;
            #pragma unroll
            for (int j = 0; j < LB; ++j) {
                float4 a = Wl4[j * (DIM / 4) + d4];
                float4 b = Wr4[j * (DIM / 4) + d4];
                h.x += m[j] * a.x + xv[j] * b.x;
                h.y += m[j] * a.y + xv[j] * b.y;
                h.z += m[j] * a.z + xv[j] * b.z;
                h.w += m[j] * a.w + xv[j] * b.w;
            }
            h.x = fmaxf(h.x, 0.f); h.y = fmaxf(h.y, 0.f);
            h.z = fmaxf(h.z, 0.f); h.w = fmaxf(h.w, 0.f);
            p += h.x * ww.x + h.y * ww.y + h.z * ww.z + h.w * ww.w;
            q += ww.x * ww.x + ww.y * ww.y + ww.z * ww.z + ww.w * ww.w;
        }
        sc[t] = tanhf(p / sqrtf(q));
    }
    __syncthreads();

    {   // exact ranks (descending, ties -> lower index)
        float my = sc[t];
        int r = 0;
        const float4* sc4 = (const float4*)sc;
        #pragma unroll 4
        for (int j4 = 0; j4 < NPG1 / 4; ++j4) {
            float4 v = sc4[j4];
            int j = 4 * j4;
            r += (v.x > my) | ((v.x == my) & (j     < t));
            r += (v.y > my) | ((v.y == my) & (j + 1 < t));
            r += (v.z > my) | ((v.z == my) & (j + 2 < t));
            r += (v.w > my) | ((v.w == my) & (j + 3 < t));
        }
        rnk[t] = r;
    }
    __syncthreads();

    // CSR2 from CSR1 — atomic-free; owner thread writes its global row
    // (entries, then sentinel fill to 48; 96 B contiguous) + indeg.
    {
        const int rd = rnk[t];
        if (rd < K1) {
            const int dg1 = min(lcnt[t], CSRW1);
            unsigned short* row = csr2 + ((size_t)g * K1 + rd) * CSRW;
            int vcnt = 0;
            for (int k = 0; k < dg1; ++k) {
                int s  = lcsr1[k * NPG1 + t];
                int rs = rnk[s];
                if (rs < K1) {
                    if (vcnt < CSRW) row[vcnt] = (unsigned short)rs;
                    ++vcnt;
                }
            }
            const int vc = min(vcnt, CSRW);
            for (int k = vc; k < CSRW; ++k) row[k] = (unsigned short)K1;
            indeg[g * K1 + rd] = vc;
        }
    }

    // Kept-row recompute (lane = dim) + scaled h1p write; mx/sm in registers.
    float mx = -INFINITY, sm = 0.f;
    {
        float wlv[LB], wrv[LB];
        #pragma unroll
        for (int j = 0; j < LB; ++j) { wlv[j] = Wl[j * DIM + lane]; wrv[j] = Wr[j * DIM + lane]; }
        const float blv = bl[lane];

        for (int n = wid; n < NPG1; n += 8) {
            int r = rnk[n];
            if (r >= K1) continue;
            const float* mp = ml + n * LB;
            const float* xp = xl + n * LB;
            float al = 0.f, ar = 0.f;
            #pragma unroll
            for (int j = 0; j < LB; ++j) {
                al += mp[j] * wlv[j];
                ar += xp[j] * wrv[j];
            }
            float acc = fmaxf(blv + al + ar, 0.f);
            float v = acc * sc[n];
            h1p[((size_t)g * K1P + r) * DIM + lane] = v;
            mx = fmaxf(mx, v);
            sm += v;
        }
    }
    __syncthreads();   // all lcsr1 reads done -> safe to overlay red arrays

    redmx[wid * DIM + lane] = mx;
    redsm[wid * DIM + lane] = sm;
    __syncthreads();
    if (wid == 0) {
        float m2 = redmx[lane], s2 = redsm[lane];
        #pragma unroll
        for (int w = 1; w < 8; ++w) {
            m2 = fmaxf(m2, redmx[w * DIM + lane]);
            s2 += redsm[w * DIM + lane];
        }
        x1buf[g * 2 * DIM + lane]       = m2;
        x1buf[g * 2 * DIM + DIM + lane] = s2 * (1.0f / (float)K1);
    }
}

// ---------------------------------------------------------------------------
// gemm2 (round-13 proven version): Yl = h1p@Wl (in-place), Yr = h1p@Wr + bl.
__global__ __launch_bounds__(512)
void gemm2_kernel(float* __restrict__ hY,        // h1p in, Y_l out (in-place)
                  float* __restrict__ Yr,        // Y_r out
                  const float* __restrict__ Wl,
                  const float* __restrict__ bl,
                  const float* __restrict__ Wr) {
    __shared__ __align__(16) float wls[DIM * DIM];   // 16 KB
    __shared__ __align__(16) float wrs[DIM * DIM];   // 16 KB
    __shared__ __align__(16) float rt[64 * DIM];     // 16 KB row tile

    const int t = threadIdx.x, wid = t >> 6, lane = t & 63;
    const int nb = (int)blockIdx.x * 64;         // grid = NR/64 exact

    {
        const float4* W4l = (const float4*)Wl;
        const float4* W4r = (const float4*)Wr;
        const float4* R4  = (const float4*)&hY[(size_t)nb * DIM];
        float4* a = (float4*)wls;
        float4* b = (float4*)wrs;
        float4* r = (float4*)rt;
        #pragma unroll
        for (int k = 0; k < 2; ++k) {
            a[k * 512 + t] = W4l[k * 512 + t];
            b[k * 512 + t] = W4r[k * 512 + t];
            r[k * 512 + t] = R4[k * 512 + t];
        }
    }
    __syncthreads();

    const int r0 = wid * 8;                      // 8 rows per wave
    float accl[8] = {0.f,0.f,0.f,0.f,0.f,0.f,0.f,0.f};
    float accr[8] = {0.f,0.f,0.f,0.f,0.f,0.f,0.f,0.f};
    #pragma unroll 4
    for (int j4 = 0; j4 < DIM / 4; ++j4) {
        const int jb = 4 * j4 * DIM + lane;
        float w0 = wls[jb],           w1 = wls[jb + DIM];
        float w2 = wls[jb + 2 * DIM], w3 = wls[jb + 3 * DIM];
        float u0 = wrs[jb],           u1 = wrs[jb + DIM];
        float u2 = wrs[jb + 2 * DIM], u3 = wrs[jb + 3 * DIM];
        #pragma unroll
        for (int i = 0; i < 8; ++i) {
            float4 a = *(const float4*)&rt[(r0 + i) * DIM + 4 * j4];
            accl[i] += a.x * w0 + a.y * w1 + a.z * w2 + a.w * w3;
            accr[i] += a.x * u0 + a.y * u1 + a.z * u2 + a.w * u3;
        }
    }
    const float bv = bl[lane];
    #pragma unroll
    for (int i = 0; i < 8; ++i) {
        hY[(size_t)(nb + r0 + i) * DIM + lane] = accl[i];
        Yr[(size_t)(nb + r0 + i) * DIM + lane] = accr[i] + bv;
    }
}

// ---------------------------------------------------------------------------
// gather2: h2 = relu(invd * sum(Y_l[nbr]) + Y_r) in-place over Yr, + score2.
__global__ __launch_bounds__(256)
void gather2_kernel(const float* __restrict__ Yl,
                    float* __restrict__ Yh,      // Y_r in, h2 out (in-place)
                    const unsigned short* __restrict__ csr2,
                    const int* __restrict__ indeg,
                    const float* __restrict__ pw,
                    float* __restrict__ sc2g) {
    const int t = threadIdx.x, wid = t >> 6, lane = t & 63;
    const int cid = ((int)blockIdx.x & 7) * (GRIDA / 8) + ((int)blockIdx.x >> 3);
    const int nb = __builtin_amdgcn_readfirstlane(cid * 16 + wid * 4);

    const float pwv = pw[lane];
    float q = pwv * pwv;
    #pragma unroll
    for (int o = 32; o; o >>= 1) q += __shfl_xor(q, o);
    const float inv_nrm = 1.f / sqrtf(q);

    #pragma unroll
    for (int i = 0; i < 4; ++i) {
        const int n  = nb + i;
        const int dg = indeg[n];
        const int g  = n / K1;                   // scalar magic-mul div
        const int lr = n - g * K1;
        const float* __restrict__ bp = Yl + (size_t)g * K1P * DIM;  // scalar base
        const int4* cr = (const int4*)(csr2 + (size_t)n * CSRW);
        float a0 = 0.f, a1 = 0.f;
        const int it = (dg + 7) >> 3;
        for (int kc = 0; kc < it; ++kc) {
            int4 wv = cr[kc];                    // u16 values <= K1 (sign-safe)
            a0 += bp[((wv.x & 0xffff) << 6) + lane];
            a1 += bp[((wv.x >> 16)    << 6) + lane];
            a0 += bp[((wv.y & 0xffff) << 6) + lane];
            a1 += bp[((wv.y >> 16)    << 6) + lane];
            a0 += bp[((wv.z & 0xffff) << 6) + lane];
            a1 += bp[((wv.z >> 16)    << 6) + lane];
            a0 += bp[((wv.w & 0xffff) << 6) + lane];
            a1 += bp[((wv.w >> 16)    << 6) + lane];
        }
        const float invd = 1.f / fmaxf((float)dg, 1.f);
        float* yrow = Yh + (size_t)(g * K1P + lr) * DIM;
        const float h = fmaxf((a0 + a1) * invd + yrow[lane], 0.f);
        yrow[lane] = h;
        float p = h * pwv;
        #pragma unroll
        for (int o = 32; o; o >>= 1) p += __shfl_xor(p, o);
        if (lane == 0) sc2g[n] = tanhf(p * inv_nrm);
    }
}

// ---------------------------------------------------------------------------
// Pool2 + readout2 + final MLP (one block per graph). h2 rows at stride K1P.
__global__ __launch_bounds__(512)
void pool2_mlp_kernel(const float* __restrict__ sc2g,
                      const float* __restrict__ h2,
                      const float* __restrict__ x1buf,
                      const float* __restrict__ W1,
                      const float* __restrict__ b1,
                      const float* __restrict__ W2,
                      const float* __restrict__ b2,
                      float* __restrict__ out) {
    __shared__ __align__(16) float sc2[412];
    __shared__ int   rnk2[K1];
    __shared__ float redmx[8 * DIM];
    __shared__ float redsm[8 * DIM];
    __shared__ float zy[2 * DIM + DIM];

    const int g = blockIdx.x, t = threadIdx.x;
    const int wid = t >> 6, lane = t & 63;

    if (t < K1) sc2[t] = sc2g[g * K1 + t];
    if (t >= K1 && t < 412) sc2[t] = -INFINITY;
    __syncthreads();

    if (t < K1) {
        float my = sc2[t];
        int r = 0;
        const float4* sc4 = (const float4*)sc2;
        #pragma unroll 4
        for (int j4 = 0; j4 < 103; ++j4) {
            float4 v = sc4[j4];
            int j = 4 * j4;
            r += (v.x > my) | ((v.x == my) & (j     < t));
            r += (v.y > my) | ((v.y == my) & (j + 1 < t));
            r += (v.z > my) | ((v.z == my) & (j + 2 < t));
            r += (v.w > my) | ((v.w == my) & (j + 3 < t));
        }
        rnk2[t] = r;
    }
    __syncthreads();

    float mx = -INFINITY, sm = 0.f;
    for (int n = wid; n < K1; n += 8) {
        if (rnk2[n] < K2) {
            float v = h2[((size_t)g * K1P + n) * DIM + lane] * sc2[n];
            mx = fmaxf(mx, v);
            sm += v;
        }
    }
    redmx[wid * DIM + lane] = mx;
    redsm[wid * DIM + lane] = sm;
    __syncthreads();
    if (wid == 0) {
        float m2 = redmx[lane], s2 = redsm[lane];
        #pragma unroll
        for (int w = 1; w < 8; ++w) {
            m2 = fmaxf(m2, redmx[w * DIM + lane]);
            s2 += redsm[w * DIM + lane];
        }
        zy[lane]       = x1buf[g * 2 * DIM + lane]       + m2;
        zy[DIM + lane] = x1buf[g * 2 * DIM + DIM + lane] + s2 * (1.0f / (float)K2);
    }
    __syncthreads();

    if (t < DIM) {
        float a = b1[t];
        #pragma unroll 8
        for (int j = 0; j < 2 * DIM; ++j) a += zy[j] * W1[j * DIM + t];
        zy[2 * DIM + t] = fmaxf(a, 0.f);
    }
    __syncthreads();
    if (t < OUTF) {
        float a = b2[t];
        #pragma unroll
        for (int j = 0; j < DIM; ++j) a += zy[2 * DIM + j] * W2[j * OUTF + t];
        out[g * OUTF + t] = a;
    }
}

// ---------------------------------------------------------------------------
extern "C" void kernel_launch(void* const* d_in, const int* in_sizes, int n_in,
                              void* d_out, int out_size, void* d_ws, size_t ws_size,
                              hipStream_t stream) {
    (void)in_sizes; (void)n_in; (void)out_size; (void)ws_size;
    const float* x       = (const float*)d_in[0];
    const int*   eidx    = (const int*)d_in[1];
    const float* c1_Wl   = (const float*)d_in[2];
    const float* c1_bl   = (const float*)d_in[3];
    const float* c1_Wr   = (const float*)d_in[4];
    const float* pool1_w = (const float*)d_in[5];
    const float* c2_Wl   = (const float*)d_in[6];
    const float* c2_bl   = (const float*)d_in[7];
    const float* c2_Wr   = (const float*)d_in[8];
    const float* pool2_w = (const float*)d_in[9];
    const float* lin1_W  = (const float*)d_in[10];
    const float* lin1_b  = (const float*)d_in[11];
    const float* lin2_W  = (const float*)d_in[12];
    const float* lin2_b  = (const float*)d_in[13];
    float* out = (float*)d_out;

    // Workspace layout (256-aligned), ~65 MB
    char* w = (char*)d_ws;
    size_t off = 0;
    auto alloc = [&](size_t bytes) {
        void* p = w + off;
        off = (off + bytes + 255) & ~(size_t)255;
        return p;
    };
    float* h1p   = (float*)alloc((size_t)NR * DIM * 4);        // 26.9 MB; becomes Y_l
    float* x1buf = (float*)alloc((size_t)BGR * 2 * DIM * 4);   // 128 KB
    float* sc2g  = (float*)alloc((size_t)N1 * 4);              // 410 KB
    int*   indeg = (int*)  alloc((size_t)N1 * 4);              // 410 KB
    float* Yh    = (float*)alloc((size_t)NR * DIM * 4);        // 26.9 MB; Y_r -> h2
    unsigned short* csr2 = (unsigned short*)alloc((size_t)N1 * CSRW * 2); // 10.1 MB

    float* Yl = h1p;                                           // in-place

    s1_mega_kernel<<<BGR, 512, 0, stream>>>(x, eidx, c1_Wl, c1_bl, c1_Wr,
                                            pool1_w, h1p, x1buf, csr2, indeg);
    gemm2_kernel<<<GRIDW, 512, 0, stream>>>(h1p, Yh, c2_Wl, c2_bl, c2_Wr);
    gather2_kernel<<<GRIDA, 256, 0, stream>>>(Yl, Yh, csr2, indeg, pool2_w, sc2g);
    pool2_mlp_kernel<<<BGR, 512, 0, stream>>>(sc2g, Yh, x1buf, lin1_W, lin1_b,
                                              lin2_W, lin2_b, out);
}

// Round 20
// 158.645 us; speedup vs baseline: 1.0930x; 1.0930x over previous
//
#include <hip/hip_runtime.h>
#include <hip/hip_bf16.h>

// Problem constants
#define BGR   256                 // graphs
#define NPG1  512                 // nodes per graph (input)
#define DEG   16
#define EPG   (NPG1 * DEG)        // 8192 edges per graph
#define LB    5                   // lookback features
#define DIM   64
#define OUTF  6
#define NN    (BGR * NPG1)        // 131,072
#define EDG   (BGR * EPG)         // 2,097,152
#define K1    410                 // ceil(0.8*512)
#define K2    328                 // ceil(0.8*410)
#define N1    (BGR * K1)          // 104,960 (compact node space)
#define K1P   (K1 + 1)            // padded stride: row K1 of each graph = zeros
#define NR    (BGR * K1P)         // 105,216 padded rows (= 1644 * 64)
#define CSRW  48                  // layer-2 CSR slots per pooled node
#define CSRW1 52                  // layer-1 CSR slots (P[in-deg>52] ~ 3e-8)
#define GRIDW (NR / 64)           // 1644 gemm blocks (64 rows each)
#define GRIDA (N1 / 16)           // 6560 gather2 blocks

// ---------------------------------------------------------------------------
// s1_mega (one 1024-thread block per graph; 16 waves = 4 waves/SIMD):
// stage x -> CSR1 build (8 edges/thr) -> conv1 score (thread-PAIR gather
// split) -> rank (pair scan split) -> CSR2 derive (owner, LDS) -> kept-row
// recompute (16 waves) -> coalesced CSR2/indeg writeout + readout x1.
// LDS ~120 KB.
__global__ __launch_bounds__(1024)
void s1_mega_kernel(const float* __restrict__ x,
                    const int* __restrict__ eidx,
                    const float* __restrict__ Wl,
                    const float* __restrict__ bl,
                    const float* __restrict__ Wr,
                    const float* __restrict__ pw,
                    float* __restrict__ h1p,
                    float* __restrict__ x1buf,
                    unsigned short* __restrict__ csr2,
                    int* __restrict__ indeg) {
    __shared__ __align__(16) float xl[NPG1 * LB];                // 10 KB
    __shared__ __align__(16) float ml[NPG1 * LB];                // 10 KB
    __shared__ __align__(16) unsigned short lcsr1[CSRW1 * NPG1]; // 53.25 KB
    __shared__ int   lcnt[NPG1];                                 // 2 KB
    __shared__ __align__(16) float sc[NPG1];                     // 2 KB
    __shared__ int   rnk[NPG1];                                  // 2 KB
    __shared__ int   rhelp[NPG1];                                // 2 KB
    __shared__ __align__(16) unsigned short lcsr2[K1 * CSRW];    // 39.4 KB
    __shared__ int   lcnt2[K1];                                  // 1.6 KB
    // reduction arrays overlay lcsr1 (dead after CSR2 derive; barrier-guarded)
    float* redmx = (float*)lcsr1;                                // 4 KB
    float* redsm = redmx + 16 * DIM;                             // 4 KB

    const int g = blockIdx.x, t = threadIdx.x;     // t in [0,1024)
    const int wid = t >> 6, lane = t & 63;
    const int n9 = t & (NPG1 - 1);                 // owned node
    const int half = t >> 9;                       // 0 = owner, 1 = helper
    const int* __restrict__ src = eidx;
    const int* __restrict__ dst = eidx + EDG;

    {   // stage x, init counters, sentinel-prefill CSR2, zero h1p pad row
        const float4* x4 = (const float4*)(x + (size_t)g * (NPG1 * LB));
        float4* xl4 = (float4*)xl;
        if (t < NPG1 * LB / 4) xl4[t] = x4[t];
        if (t < NPG1) lcnt[t] = 0;
        const int fill = (K1 << 16) | K1;
        int* li = (int*)lcsr2;
        for (int i = t; i < K1 * CSRW / 2; i += 1024) li[i] = fill;
        if (t < DIM) h1p[((size_t)g * K1P + K1) * DIM + t] = 0.f;
    }
    __syncthreads();

    // Edge pass: build CSR1 [slot][node] in LDS (8 edges per thread).
    const int ebase = g * EPG;
    #pragma unroll
    for (int k = 0; k < EPG / 1024; ++k) {
        int e = ebase + k * 1024 + t;
        int s = src[e] & (NPG1 - 1);
        int d = dst[e] & (NPG1 - 1);
        int slot = atomicAdd(&lcnt[d], 1);
        if (slot < CSRW1) lcsr1[slot * NPG1 + d] = (unsigned short)s;
    }
    __syncthreads();

    // Score: pair-split neighbor gather (owner even slots, helper odd).
    {
        const int dgf = lcnt[n9];
        const int dg  = min(dgf, CSRW1);
        float s0 = 0.f, s1 = 0.f, s2 = 0.f, s3 = 0.f, s4 = 0.f;
        for (int k = half; k < dg; k += 2) {
            int s = lcsr1[k * NPG1 + n9];
            const float* xp = xl + s * LB;
            s0 += xp[0]; s1 += xp[1]; s2 += xp[2]; s3 += xp[3]; s4 += xp[4];
        }
        if (half == 1) {
            float* mp = ml + n9 * LB;
            mp[0] = s0; mp[1] = s1; mp[2] = s2; mp[3] = s3; mp[4] = s4;
        }
        __syncthreads();
        if (half == 0) {
            float* mp = ml + n9 * LB;
            s0 += mp[0]; s1 += mp[1]; s2 += mp[2]; s3 += mp[3]; s4 += mp[4];
            const float invd = 1.f / fmaxf((float)dgf, 1.f);
            float m[LB]  = { s0 * invd, s1 * invd, s2 * invd, s3 * invd, s4 * invd };
            float xv[LB];
            #pragma unroll
            for (int j = 0; j < LB; ++j) { xv[j] = xl[n9 * LB + j]; mp[j] = m[j]; }

            const float4* Wl4 = (const float4*)Wl;
            const float4* Wr4 = (const float4*)Wr;
            const float4* bl4 = (const float4*)bl;
            const float4* pw4 = (const float4*)pw;
            float p = 0.f, q = 0.f;
            #pragma unroll 4
            for (int d4 = 0; d4 < DIM / 4; ++d4) {
                float4 bb = bl4[d4];
                float4 ww = pw4[d4];
                float4 h = bb;
                #pragma unroll
                for (int j = 0; j < LB; ++j) {
                    float4 a = Wl4[j * (DIM / 4) + d4];
                    float4 b = Wr4[j * (DIM / 4) + d4];
                    h.x += m[j] * a.x + xv[j] * b.x;
                    h.y += m[j] * a.y + xv[j] * b.y;
                    h.z += m[j] * a.z + xv[j] * b.z;
                    h.w += m[j] * a.w + xv[j] * b.w;
                }
                h.x = fmaxf(h.x, 0.f); h.y = fmaxf(h.y, 0.f);
                h.z = fmaxf(h.z, 0.f); h.w = fmaxf(h.w, 0.f);
                p += h.x * ww.x + h.y * ww.y + h.z * ww.z + h.w * ww.w;
                q += ww.x * ww.x + ww.y * ww.y + ww.z * ww.z + ww.w * ww.w;
            }
            sc[n9] = tanhf(p / sqrtf(q));
        }
    }
    __syncthreads();

    // Rank: pair-split scan (owner j4 0..63, helper 64..127), combine.
    {
        float my = sc[n9];
        int r = 0;
        const float4* sc4 = (const float4*)sc;
        const int j0 = half * (NPG1 / 8);          // 64 float4 per half
        #pragma unroll 4
        for (int j4 = j0; j4 < j0 + NPG1 / 8; ++j4) {
            float4 v = sc4[j4];
            int j = 4 * j4;
            r += (v.x > my) | ((v.x == my) & (j     < n9));
            r += (v.y > my) | ((v.y == my) & (j + 1 < n9));
            r += (v.z > my) | ((v.z == my) & (j + 2 < n9));
            r += (v.w > my) | ((v.w == my) & (j + 3 < n9));
        }
        if (half == 1) rhelp[n9] = r;
        __syncthreads();
        if (half == 0) rnk[n9] = r + rhelp[n9];
    }
    __syncthreads();

    // CSR2 from CSR1 — atomic-free; owner thread per dst node, into LDS.
    if (half == 0) {
        const int rd = rnk[n9];
        if (rd < K1) {
            const int dg1 = min(lcnt[n9], CSRW1);
            int vcnt = 0;
            for (int k = 0; k < dg1; ++k) {
                int s  = lcsr1[k * NPG1 + n9];
                int rs = rnk[s];
                if (rs < K1) {
                    if (vcnt < CSRW) lcsr2[rd * CSRW + vcnt] = (unsigned short)rs;
                    ++vcnt;
                }
            }
            lcnt2[rd] = min(vcnt, CSRW);
        }
    }

    // Kept-row recompute (lane = dim, 16 waves) + scaled h1p write.
    float mx = -INFINITY, sm = 0.f;
    {
        float wlv[LB], wrv[LB];
        #pragma unroll
        for (int j = 0; j < LB; ++j) { wlv[j] = Wl[j * DIM + lane]; wrv[j] = Wr[j * DIM + lane]; }
        const float blv = bl[lane];

        for (int n = wid; n < NPG1; n += 16) {
            int r = rnk[n];
            if (r >= K1) continue;
            const float* mp = ml + n * LB;
            const float* xp = xl + n * LB;
            float al = 0.f, ar = 0.f;
            #pragma unroll
            for (int j = 0; j < LB; ++j) {
                al += mp[j] * wlv[j];
                ar += xp[j] * wrv[j];
            }
            float acc = fmaxf(blv + al + ar, 0.f);
            float v = acc * sc[n];
            h1p[((size_t)g * K1P + r) * DIM + lane] = v;
            mx = fmaxf(mx, v);
            sm += v;
        }
    }
    __syncthreads();   // lcsr1 reads + lcsr2/lcnt2 writes all complete

    redmx[wid * DIM + lane] = mx;
    redsm[wid * DIM + lane] = sm;
    __syncthreads();
    if (wid == 0) {
        float m2 = redmx[lane], s2 = redsm[lane];
        #pragma unroll
        for (int w = 1; w < 16; ++w) {
            m2 = fmaxf(m2, redmx[w * DIM + lane]);
            s2 += redsm[w * DIM + lane];
        }
        x1buf[g * 2 * DIM + lane]       = m2;
        x1buf[g * 2 * DIM + DIM + lane] = s2 * (1.0f / (float)K1);
    }

    {   // coalesced CSR2 + indeg writeout (1024 threads)
        const int4* ls4 = (const int4*)lcsr2;
        int4* gs4 = (int4*)(csr2 + (size_t)g * K1 * CSRW);
        for (int i = t; i < K1 * CSRW / 8; i += 1024) gs4[i] = ls4[i];
        if (t < K1) indeg[g * K1 + t] = lcnt2[t];
    }
}

// ---------------------------------------------------------------------------
// gemm2 (round-13 proven version): Yl = h1p@Wl (in-place), Yr = h1p@Wr + bl.
__global__ __launch_bounds__(512)
void gemm2_kernel(float* __restrict__ hY,        // h1p in, Y_l out (in-place)
                  float* __restrict__ Yr,        // Y_r out
                  const float* __restrict__ Wl,
                  const float* __restrict__ bl,
                  const float* __restrict__ Wr) {
    __shared__ __align__(16) float wls[DIM * DIM];   // 16 KB
    __shared__ __align__(16) float wrs[DIM * DIM];   // 16 KB
    __shared__ __align__(16) float rt[64 * DIM];     // 16 KB row tile

    const int t = threadIdx.x, wid = t >> 6, lane = t & 63;
    const int nb = (int)blockIdx.x * 64;         // grid = NR/64 exact

    {
        const float4* W4l = (const float4*)Wl;
        const float4* W4r = (const float4*)Wr;
        const float4* R4  = (const float4*)&hY[(size_t)nb * DIM];
        float4* a = (float4*)wls;
        float4* b = (float4*)wrs;
        float4* r = (float4*)rt;
        #pragma unroll
        for (int k = 0; k < 2; ++k) {
            a[k * 512 + t] = W4l[k * 512 + t];
            b[k * 512 + t] = W4r[k * 512 + t];
            r[k * 512 + t] = R4[k * 512 + t];
        }
    }
    __syncthreads();

    const int r0 = wid * 8;                      // 8 rows per wave
    float accl[8] = {0.f,0.f,0.f,0.f,0.f,0.f,0.f,0.f};
    float accr[8] = {0.f,0.f,0.f,0.f,0.f,0.f,0.f,0.f};
    #pragma unroll 4
    for (int j4 = 0; j4 < DIM / 4; ++j4) {
        const int jb = 4 * j4 * DIM + lane;
        float w0 = wls[jb],           w1 = wls[jb + DIM];
        float w2 = wls[jb + 2 * DIM], w3 = wls[jb + 3 * DIM];
        float u0 = wrs[jb],           u1 = wrs[jb + DIM];
        float u2 = wrs[jb + 2 * DIM], u3 = wrs[jb + 3 * DIM];
        #pragma unroll
        for (int i = 0; i < 8; ++i) {
            float4 a = *(const float4*)&rt[(r0 + i) * DIM + 4 * j4];
            accl[i] += a.x * w0 + a.y * w1 + a.z * w2 + a.w * w3;
            accr[i] += a.x * u0 + a.y * u1 + a.z * u2 + a.w * u3;
        }
    }
    const float bv = bl[lane];
    #pragma unroll
    for (int i = 0; i < 8; ++i) {
        hY[(size_t)(nb + r0 + i) * DIM + lane] = accl[i];
        Yr[(size_t)(nb + r0 + i) * DIM + lane] = accr[i] + bv;
    }
}

// ---------------------------------------------------------------------------
// gather2: h2 = relu(invd * sum(Y_l[nbr]) + Y_r) in-place over Yr, + score2.
__global__ __launch_bounds__(256)
void gather2_kernel(const float* __restrict__ Yl,
                    float* __restrict__ Yh,      // Y_r in, h2 out (in-place)
                    const unsigned short* __restrict__ csr2,
                    const int* __restrict__ indeg,
                    const float* __restrict__ pw,
                    float* __restrict__ sc2g) {
    const int t = threadIdx.x, wid = t >> 6, lane = t & 63;
    const int cid = ((int)blockIdx.x & 7) * (GRIDA / 8) + ((int)blockIdx.x >> 3);
    const int nb = __builtin_amdgcn_readfirstlane(cid * 16 + wid * 4);

    const float pwv = pw[lane];
    float q = pwv * pwv;
    #pragma unroll
    for (int o = 32; o; o >>= 1) q += __shfl_xor(q, o);
    const float inv_nrm = 1.f / sqrtf(q);

    #pragma unroll
    for (int i = 0; i < 4; ++i) {
        const int n  = nb + i;
        const int dg = indeg[n];
        const int g  = n / K1;                   // scalar magic-mul div
        const int lr = n - g * K1;
        const float* __restrict__ bp = Yl + (size_t)g * K1P * DIM;  // scalar base
        const int4* cr = (const int4*)(csr2 + (size_t)n * CSRW);
        float a0 = 0.f, a1 = 0.f;
        const int it = (dg + 7) >> 3;
        for (int kc = 0; kc < it; ++kc) {
            int4 wv = cr[kc];                    // u16 values <= K1 (sign-safe)
            a0 += bp[((wv.x & 0xffff) << 6) + lane];
            a1 += bp[((wv.x >> 16)    << 6) + lane];
            a0 += bp[((wv.y & 0xffff) << 6) + lane];
            a1 += bp[((wv.y >> 16)    << 6) + lane];
            a0 += bp[((wv.z & 0xffff) << 6) + lane];
            a1 += bp[((wv.z >> 16)    << 6) + lane];
            a0 += bp[((wv.w & 0xffff) << 6) + lane];
            a1 += bp[((wv.w >> 16)    << 6) + lane];
        }
        const float invd = 1.f / fmaxf((float)dg, 1.f);
        float* yrow = Yh + (size_t)(g * K1P + lr) * DIM;
        const float h = fmaxf((a0 + a1) * invd + yrow[lane], 0.f);
        yrow[lane] = h;
        float p = h * pwv;
        #pragma unroll
        for (int o = 32; o; o >>= 1) p += __shfl_xor(p, o);
        if (lane == 0) sc2g[n] = tanhf(p * inv_nrm);
    }
}

// ---------------------------------------------------------------------------
// Pool2 + readout2 + final MLP (one block per graph). h2 rows at stride K1P.
__global__ __launch_bounds__(512)
void pool2_mlp_kernel(const float* __restrict__ sc2g,
                      const float* __restrict__ h2,
                      const float* __restrict__ x1buf,
                      const float* __restrict__ W1,
                      const float* __restrict__ b1,
                      const float* __restrict__ W2,
                      const float* __restrict__ b2,
                      float* __restrict__ out) {
    __shared__ __align__(16) float sc2[412];
    __shared__ int   rnk2[K1];
    __shared__ float redmx[8 * DIM];
    __shared__ float redsm[8 * DIM];
    __shared__ float zy[2 * DIM + DIM];

    const int g = blockIdx.x, t = threadIdx.x;
    const int wid = t >> 6, lane = t & 63;

    if (t < K1) sc2[t] = sc2g[g * K1 + t];
    if (t >= K1 && t < 412) sc2[t] = -INFINITY;
    __syncthreads();

    if (t < K1) {
        float my = sc2[t];
        int r = 0;
        const float4* sc4 = (const float4*)sc2;
        #pragma unroll 4
        for (int j4 = 0; j4 < 103; ++j4) {
            float4 v = sc4[j4];
            int j = 4 * j4;
            r += (v.x > my) | ((v.x == my) & (j     < t));
            r += (v.y > my) | ((v.y == my) & (j + 1 < t));
            r += (v.z > my) | ((v.z == my) & (j + 2 < t));
            r += (v.w > my) | ((v.w == my) & (j + 3 < t));
        }
        rnk2[t] = r;
    }
    __syncthreads();

    float mx = -INFINITY, sm = 0.f;
    for (int n = wid; n < K1; n += 8) {
        if (rnk2[n] < K2) {
            float v = h2[((size_t)g * K1P + n) * DIM + lane] * sc2[n];
            mx = fmaxf(mx, v);
            sm += v;
        }
    }
    redmx[wid * DIM + lane] = mx;
    redsm[wid * DIM + lane] = sm;
    __syncthreads();
    if (wid == 0) {
        float m2 = redmx[lane], s2 = redsm[lane];
        #pragma unroll
        for (int w = 1; w < 8; ++w) {
            m2 = fmaxf(m2, redmx[w * DIM + lane]);
            s2 += redsm[w * DIM + lane];
        }
        zy[lane]       = x1buf[g * 2 * DIM + lane]       + m2;
        zy[DIM + lane] = x1buf[g * 2 * DIM + DIM + lane] + s2 * (1.0f / (float)K2);
    }
    __syncthreads();

    if (t < DIM) {
        float a = b1[t];
        #pragma unroll 8
        for (int j = 0; j < 2 * DIM; ++j) a += zy[j] * W1[j * DIM + t];
        zy[2 * DIM + t] = fmaxf(a, 0.f);
    }
    __syncthreads();
    if (t < OUTF) {
        float a = b2[t];
        #pragma unroll
        for (int j = 0; j < DIM; ++j) a += zy[2 * DIM + j] * W2[j * OUTF + t];
        out[g * OUTF + t] = a;
    }
}

// ---------------------------------------------------------------------------
extern "C" void kernel_launch(void* const* d_in, const int* in_sizes, int n_in,
                              void* d_out, int out_size, void* d_ws, size_t ws_size,
                              hipStream_t stream) {
    (void)in_sizes; (void)n_in; (void)out_size; (void)ws_size;
    const float* x       = (const float*)d_in[0];
    const int*   eidx    = (const int*)d_in[1];
    const float* c1_Wl   = (const float*)d_in[2];
    const float* c1_bl   = (const float*)d_in[3];
    const float* c1_Wr   = (const float*)d_in[4];
    const float* pool1_w = (const float*)d_in[5];
    const float* c2_Wl   = (const float*)d_in[6];
    const float* c2_bl   = (const float*)d_in[7];
    const float* c2_Wr   = (const float*)d_in[8];
    const float* pool2_w = (const float*)d_in[9];
    const float* lin1_W  = (const float*)d_in[10];
    const float* lin1_b  = (const float*)d_in[11];
    const float* lin2_W  = (const float*)d_in[12];
    const float* lin2_b  = (const float*)d_in[13];
    float* out = (float*)d_out;

    // Workspace layout (256-aligned), ~65 MB
    char* w = (char*)d_ws;
    size_t off = 0;
    auto alloc = [&](size_t bytes) {
        void* p = w + off;
        off = (off + bytes + 255) & ~(size_t)255;
        return p;
    };
    float* h1p   = (float*)alloc((size_t)NR * DIM * 4);        // 26.9 MB; becomes Y_l
    float* x1buf = (float*)alloc((size_t)BGR * 2 * DIM * 4);   // 128 KB
    float* sc2g  = (float*)alloc((size_t)N1 * 4);              // 410 KB
    int*   indeg = (int*)  alloc((size_t)N1 * 4);              // 410 KB
    float* Yh    = (float*)alloc((size_t)NR * DIM * 4);        // 26.9 MB; Y_r -> h2
    unsigned short* csr2 = (unsigned short*)alloc((size_t)N1 * CSRW * 2); // 10.1 MB

    float* Yl = h1p;                                           // in-place

    s1_mega_kernel<<<BGR, 1024, 0, stream>>>(x, eidx, c1_Wl, c1_bl, c1_Wr,
                                             pool1_w, h1p, x1buf, csr2, indeg);
    gemm2_kernel<<<GRIDW, 512, 0, stream>>>(h1p, Yh, c2_Wl, c2_bl, c2_Wr);
    gather2_kernel<<<GRIDA, 256, 0, stream>>>(Yl, Yh, csr2, indeg, pool2_w, sc2g);
    pool2_mlp_kernel<<<BGR, 512, 0, stream>>>(sc2g, Yh, x1buf, lin1_W, lin1_b,
                                              lin2_W, lin2_b, out);
}